// Round 5
// baseline (232.027 us; speedup 1.0000x reference)
//
#include <hip/hip_runtime.h>
#include <hip/hip_bf16.h>

#define ENC 2048
#define ADIM 512
#define DEC 512
#define NBATCH 128
#define NL 196
#define MTOT (NBATCH * NL)   // 25088
#define NKT 32               // K-steps of 64

typedef __attribute__((ext_vector_type(8))) short short8;
typedef __attribute__((ext_vector_type(4))) float f32x4;
typedef __attribute__((ext_vector_type(4))) unsigned int u32x4;

__device__ __forceinline__ unsigned short f2bf(float f) {
    __hip_bfloat16 h = __float2bfloat16(f);
    union { __hip_bfloat16 h; unsigned short u; } cv; cv.h = h; return cv.u;
}
__device__ __forceinline__ unsigned int f2bf2(float lo, float hi) {
    __hip_bfloat162 h = __float22bfloat162_rn(float2{lo, hi});
    union { __hip_bfloat162 h; unsigned int u; } cv; cv.h = h; return cv.u;
}

// async global -> LDS, 16B per lane. lds pointer must be wave-uniform.
__device__ __forceinline__ void load_lds16(const void* g, void* l) {
    __builtin_amdgcn_global_load_lds(
        (const __attribute__((address_space(1))) unsigned int*)g,
        (__attribute__((address_space(3))) unsigned int*)l, 16, 0, 0);
}

// ---------------- kernel 1: w_ah = hidden @ W_w + W_b  [128 x 512] ----------------
__global__ void wah_kernel(const float* __restrict__ hidden, const float* __restrict__ Ww,
                           const float* __restrict__ Wb, float* __restrict__ wah) {
    __shared__ __align__(16) float hs[DEC];
    const int b = blockIdx.x, a = threadIdx.x;   // block 512 threads
    hs[a] = hidden[b * DEC + a];
    __syncthreads();
    float acc = Wb[a];
    #pragma unroll 4
    for (int d = 0; d < DEC; d += 4) {
        f32x4 h = *(const f32x4*)&hs[d];
        acc += h.x * Ww[(d    ) * ADIM + a];
        acc += h.y * Ww[(d + 1) * ADIM + a];
        acc += h.z * Ww[(d + 2) * ADIM + a];
        acc += h.w * Ww[(d + 3) * ADIM + a];
    }
    wah[b * ADIM + a] = acc;
}

// ---------------- kernel 2: U_w [K=2048][N=512] fp32 -> uwT [N][K] bf16 ----------------
__global__ void transpose_uw(const float* __restrict__ Uw, unsigned short* __restrict__ uwT) {
    __shared__ float t[32][33];
    const int k0 = blockIdx.x * 32, n0 = blockIdx.y * 32;
    const int tx = threadIdx.x, ty = threadIdx.y;   // 32 x 8
    #pragma unroll
    for (int i = 0; i < 4; ++i)
        t[ty + 8 * i][tx] = Uw[(size_t)(k0 + ty + 8 * i) * ADIM + n0 + tx];
    __syncthreads();
    #pragma unroll
    for (int i = 0; i < 4; ++i)
        uwT[(size_t)(n0 + ty + 8 * i) * ENC + k0 + tx] = f2bf(t[tx][ty + 8 * i]);
}

// ---------------- kernel 3: fused GEMM + tanh + A_w-dot -> score partials ----------------
// BK=64 counted-vmcnt pipeline: 32 K-steps, 32 MFMAs/wave/step (2x overhead
// amortization vs BK=32). A reg-staged (global->reg->cvt bf16->ds_write),
// B via global_load_lds DMA (pre-swizzled source, linear dest). Four named
// LDS buffers keep alias analysis exact (no spurious vmcnt(0)).
// Tiles [128 rows][64 k] bf16 = 128B rows; swizzle: 16B-slot ^= (row&7).
// Steady state outstanding at wait: B(t)4 + A(t+1)8 + B(t+1)4 + A(t+2)8 = 24
// -> s_waitcnt vmcnt(20) drains exactly B(t).
__global__ __launch_bounds__(256, 2) void gemm_score_kernel(
    const float* __restrict__ feat, const unsigned short* __restrict__ uwT,
    const float* __restrict__ Ub, const float* __restrict__ wahb,
    const float* __restrict__ Aw, float* __restrict__ part)
{
    __shared__ __align__(16) unsigned char Ab0[16384];
    __shared__ __align__(16) unsigned char Ab1[16384];
    __shared__ __align__(16) unsigned char Bb0[16384];
    __shared__ __align__(16) unsigned char Bb1[16384];

    const int tid  = threadIdx.x;
    const int lane = tid & 63;
    const int w    = tid >> 6;
    const int wr   = w >> 1, wc = w & 1;
    const int l15  = lane & 15, ldr = lane >> 4;

    // bijective XCD swizzle: 784 blocks = 8 XCD chunks of 98 (nbk fastest -> 4 nbk share A-panel in L2)
    const int bid  = blockIdx.x;
    const int work = (bid & 7) * 98 + (bid >> 3);
    const int mb   = work >> 2;    // 0..195
    const int nbk  = work & 3;     // 0..3

    // ---- A global source: thread -> row tid>>1, k-half h_*32 floats ----
    const int r_ = tid >> 1, h_ = tid & 1;
    const float* aSrc = feat + (size_t)(mb * 128 + r_) * ENC + h_ * 32;
    // ---- A ds_write offsets (slot ^= row&7), 4 x b128 per thread ----
    int wA[4];
    #pragma unroll
    for (int j = 0; j < 4; ++j)
        wA[j] = r_ * 128 + (((h_ * 4 + j) ^ (r_ & 7)) << 4);

    // ---- B DMA: 4 chunks/wave of 8 rows (1KB); lane -> row lane>>3, slot lane&7 (linear dest) ----
    // source pre-swizzled: k-slot = (lane&7) ^ (row&7) = (lane&7) ^ ((lane>>3)&7)
    const unsigned short* bSrc = uwT
        + (size_t)(nbk * 128 + w * 32 + (lane >> 3)) * ENC
        + (((lane & 7) ^ ((lane >> 3) & 7)) << 3);
    // chunk c adds 8 rows: + 8*ENC per chunk; dest + 1024 per chunk

    // ---- fragment read byte offsets: row r, k-slot (ks*4+ldr) ^ (r&7) ----
    int abyte[4][2], bbyte[4][2];
    #pragma unroll
    for (int f = 0; f < 4; ++f) {
        const int r = wr * 64 + f * 16 + l15;
        const int n = wc * 64 + f * 16 + l15;
        #pragma unroll
        for (int ks = 0; ks < 2; ++ks) {
            abyte[f][ks] = r * 128 + (((ks * 4 + ldr) ^ (r & 7)) << 4);
            bbyte[f][ks] = n * 128 + (((ks * 4 + ldr) ^ (n & 7)) << 4);
        }
    }

    f32x4 acc[4][4];
    #pragma unroll
    for (int i = 0; i < 4; ++i)
        #pragma unroll
        for (int j = 0; j < 4; ++j)
            acc[i][j] = (f32x4){0.f, 0.f, 0.f, 0.f};

    f32x4 a00, a01, a02, a03, a04, a05, a06, a07;   // A(t) regs, even phases
    f32x4 a10, a11, a12, a13, a14, a15, a16, a17;   // A(t) regs, odd phases

#define ISSUE_A(KTI, R0, R1, R2, R3, R4, R5, R6, R7) {                  \
    const f32x4* p = (const f32x4*)(aSrc + (size_t)(KTI) * 64);         \
    R0 = p[0]; R1 = p[1]; R2 = p[2]; R3 = p[3];                         \
    R4 = p[4]; R5 = p[5]; R6 = p[6]; R7 = p[7];                         \
    __builtin_amdgcn_sched_barrier(0);                                  \
}
#define ISSUE_B(KTI, BB) {                                              \
    _Pragma("unroll")                                                   \
    for (int c = 0; c < 4; ++c)                                         \
        load_lds16(bSrc + (size_t)(KTI) * 64 + c * 8 * ENC,             \
                   (BB) + w * 4096 + c * 1024);                         \
    __builtin_amdgcn_sched_barrier(0);                                  \
}
#define CVT_WRITE(R0, R1, R2, R3, R4, R5, R6, R7, AB) {                 \
    u32x4 w0, w1, w2, w3;                                               \
    w0.x = f2bf2(R0.x, R0.y); w0.y = f2bf2(R0.z, R0.w);                 \
    w0.z = f2bf2(R1.x, R1.y); w0.w = f2bf2(R1.z, R1.w);                 \
    w1.x = f2bf2(R2.x, R2.y); w1.y = f2bf2(R2.z, R2.w);                 \
    w1.z = f2bf2(R3.x, R3.y); w1.w = f2bf2(R3.z, R3.w);                 \
    w2.x = f2bf2(R4.x, R4.y); w2.y = f2bf2(R4.z, R4.w);                 \
    w2.z = f2bf2(R5.x, R5.y); w2.w = f2bf2(R5.z, R5.w);                 \
    w3.x = f2bf2(R6.x, R6.y); w3.y = f2bf2(R6.z, R6.w);                 \
    w3.z = f2bf2(R7.x, R7.y); w3.w = f2bf2(R7.z, R7.w);                 \
    *(u32x4*)((AB) + wA[0]) = w0;                                       \
    *(u32x4*)((AB) + wA[1]) = w1;                                       \
    *(u32x4*)((AB) + wA[2]) = w2;                                       \
    *(u32x4*)((AB) + wA[3]) = w3;                                       \
}
#define COMPUTE(AB, BB) {                                               \
    __builtin_amdgcn_s_setprio(1);                                      \
    _Pragma("unroll")                                                   \
    for (int ks = 0; ks < 2; ++ks) {                                    \
        short8 af[4], bf[4];                                            \
        _Pragma("unroll")                                               \
        for (int f = 0; f < 4; ++f) {                                   \
            af[f] = *(const short8*)((AB) + abyte[f][ks]);              \
            bf[f] = *(const short8*)((BB) + bbyte[f][ks]);              \
        }                                                               \
        _Pragma("unroll")                                               \
        for (int fm = 0; fm < 4; ++fm)                                  \
            _Pragma("unroll")                                           \
            for (int fn = 0; fn < 4; ++fn)                              \
                acc[fm][fn] = __builtin_amdgcn_mfma_f32_16x16x32_bf16(  \
                    af[fm], bf[fn], acc[fm][fn], 0, 0, 0);              \
    }                                                                   \
    __builtin_amdgcn_s_setprio(0);                                      \
}
#define PHASE(T2, RA0, RA1, RA2, RA3, RA4, RA5, RA6, RA7, AB, BB) {     \
    CVT_WRITE(RA0, RA1, RA2, RA3, RA4, RA5, RA6, RA7, AB);              \
    ISSUE_A(T2, RA0, RA1, RA2, RA3, RA4, RA5, RA6, RA7);                \
    asm volatile("s_waitcnt vmcnt(20)");                                \
    __builtin_amdgcn_sched_barrier(0);                                  \
    asm volatile("s_waitcnt lgkmcnt(0)");                               \
    __builtin_amdgcn_sched_barrier(0);                                  \
    __builtin_amdgcn_s_barrier();                                       \
    COMPUTE(AB, BB);                                                    \
    __builtin_amdgcn_s_barrier();                                       \
    ISSUE_B(T2, BB);                                                    \
}

    // prologue: issue order A(0), B(0), A(1), B(1)
    ISSUE_A(0, a00, a01, a02, a03, a04, a05, a06, a07);
    ISSUE_B(0, Bb0);
    ISSUE_A(1, a10, a11, a12, a13, a14, a15, a16, a17);
    ISSUE_B(1, Bb1);

    #pragma unroll 1
    for (int kt = 0; kt < NKT; kt += 2) {
        const int k2 = (kt + 2 < NKT) ? kt + 2 : NKT - 1;
        const int k3 = (kt + 3 < NKT) ? kt + 3 : NKT - 1;
        PHASE(k2, a00, a01, a02, a03, a04, a05, a06, a07, Ab0, Bb0);
        PHASE(k3, a10, a11, a12, a13, a14, a15, a16, a17, Ab1, Bb1);
    }
#undef ISSUE_A
#undef ISSUE_B
#undef CVT_WRITE
#undef COMPUTE
#undef PHASE

    // epilogue: score partial = sum_c Aw[c] * tanh(acc + Ub[c] + wah[b][c]) over this block's 128 cols
    float ub4[4], aw4[4]; int cidx[4];
    #pragma unroll
    for (int f = 0; f < 4; ++f) {
        const int c = nbk * 128 + wc * 64 + f * 16 + l15;
        cidx[f] = c; ub4[f] = Ub[c]; aw4[f] = Aw[c];
    }
    #pragma unroll
    for (int fm = 0; fm < 4; ++fm) {
        #pragma unroll
        for (int r = 0; r < 4; ++r) {
            const int m = mb * 128 + wr * 64 + fm * 16 + ldr * 4 + r;
            const int b = m / NL;
            const float* wrow = wahb + b * ADIM;
            float s = 0.f;
            #pragma unroll
            for (int f = 0; f < 4; ++f)
                s += aw4[f] * tanhf(acc[fm][f][r] + ub4[f] + wrow[cidx[f]]);
            s += __shfl_xor(s, 1);
            s += __shfl_xor(s, 2);
            s += __shfl_xor(s, 4);
            s += __shfl_xor(s, 8);
            if (l15 == 0) part[(nbk * 2 + wc) * MTOT + m] = s;
        }
    }
}

// ---------------- kernel 4: reduce partials + softmax over L -> alpha ----------------
__global__ void softmax_kernel(const float* __restrict__ part, const float* __restrict__ Ab,
                               float* __restrict__ alpha) {
    const int b = blockIdx.x, t = threadIdx.x;   // 256 threads
    float sv = 0.f;
    if (t < NL) {
        sv = Ab[0];
        #pragma unroll
        for (int p = 0; p < 8; ++p) sv += part[p * MTOT + b * NL + t];
    }
    float v = (t < NL) ? sv : -3.4e38f;
    #pragma unroll
    for (int o = 32; o >= 1; o >>= 1) v = fmaxf(v, __shfl_xor(v, o));
    __shared__ float rm[4], rs[4];
    if ((t & 63) == 0) rm[t >> 6] = v;
    __syncthreads();
    const float bm = fmaxf(fmaxf(rm[0], rm[1]), fmaxf(rm[2], rm[3]));
    const float e = (t < NL) ? expf(sv - bm) : 0.f;
    float s = e;
    #pragma unroll
    for (int o = 32; o >= 1; o >>= 1) s += __shfl_xor(s, o);
    if ((t & 63) == 0) rs[t >> 6] = s;
    __syncthreads();
    const float bs = rs[0] + rs[1] + rs[2] + rs[3];
    if (t < NL) alpha[b * NL + t] = e / bs;
}

// ---------------- kernel 5: context[b][e] = sum_l alpha[b][l] * feat[b][l][e] ----------------
__global__ void context_kernel(const float* __restrict__ feat, const float* __restrict__ alpha,
                               float* __restrict__ ctx) {
    __shared__ float al[NL];
    const int b = blockIdx.x, chunk = blockIdx.y, t = threadIdx.x;  // 128 threads
    for (int i = t; i < NL; i += 128) al[i] = alpha[b * NL + i];
    __syncthreads();
    const int e0 = chunk * 512 + t * 4;
    const float* fp = feat + (size_t)b * NL * ENC + e0;
    f32x4 acc0 = (f32x4){0.f, 0.f, 0.f, 0.f};
    f32x4 acc1 = (f32x4){0.f, 0.f, 0.f, 0.f};
    #pragma unroll 2
    for (int l = 0; l < NL; l += 2) {
        f32x4 f0 = *(const f32x4*)(fp + (size_t)l * ENC);
        f32x4 f1 = *(const f32x4*)(fp + (size_t)(l + 1) * ENC);
        acc0 += al[l] * f0;
        acc1 += al[l + 1] * f1;
    }
    f32x4 rsum = acc0 + acc1;
    *(f32x4*)(ctx + (size_t)b * ENC + e0) = rsum;
}

extern "C" void kernel_launch(void* const* d_in, const int* in_sizes, int n_in,
                              void* d_out, int out_size, void* d_ws, size_t ws_size,
                              hipStream_t stream) {
    const float* feat   = (const float*)d_in[0];
    const float* hidden = (const float*)d_in[1];
    const float* Uw     = (const float*)d_in[2];
    const float* Ub     = (const float*)d_in[3];
    const float* Ww     = (const float*)d_in[4];
    const float* Wb     = (const float*)d_in[5];
    const float* Aw     = (const float*)d_in[6];
    const float* Ab     = (const float*)d_in[7];

    float* out   = (float*)d_out;
    float* alpha = out;              // [128*196]
    float* ctx   = out + MTOT;       // [128*2048]

    char* ws = (char*)d_ws;
    float*          wahb = (float*)ws;                                   // 256 KB
    unsigned short* uwT  = (unsigned short*)(ws + 262144);               // 2 MB
    float*          partb= (float*)(ws + 262144 + 2097152);              // 8*25088*4 = 784 KB

    wah_kernel<<<dim3(128), dim3(512), 0, stream>>>(hidden, Ww, Wb, wahb);
    transpose_uw<<<dim3(64, 16), dim3(32, 8), 0, stream>>>(Uw, uwT);
    gemm_score_kernel<<<dim3(784), dim3(256), 0, stream>>>(feat, uwT, Ub, wahb, Aw, partb);
    softmax_kernel<<<dim3(128), dim3(256), 0, stream>>>(partb, Ab, alpha);
    context_kernel<<<dim3(128, 4), dim3(128), 0, stream>>>(feat, alpha, ctx);
}

// Round 6
// 169.840 us; speedup vs baseline: 1.3661x; 1.3661x over previous
//
#include <hip/hip_runtime.h>
#include <hip/hip_bf16.h>

#define ENC 2048
#define ADIM 512
#define DEC 512
#define NBATCH 128
#define NL 196
#define MTOT (NBATCH * NL)   // 25088
#define NKT 32               // K-steps of 64
#define NPART 32             // score partial planes

typedef __attribute__((ext_vector_type(8))) short short8;
typedef __attribute__((ext_vector_type(4))) float f32x4;
typedef __attribute__((ext_vector_type(4))) unsigned int u32x4;

__device__ __forceinline__ unsigned short f2bf(float f) {
    __hip_bfloat16 h = __float2bfloat16(f);
    union { __hip_bfloat16 h; unsigned short u; } cv; cv.h = h; return cv.u;
}
__device__ __forceinline__ unsigned int f2bf2(float lo, float hi) {
    __hip_bfloat162 h = __float22bfloat162_rn(float2{lo, hi});
    union { __hip_bfloat162 h; unsigned int u; } cv; cv.h = h; return cv.u;
}

// async global -> LDS, 16B per lane. lds pointer must be wave-uniform.
__device__ __forceinline__ void load_lds16(const void* g, void* l) {
    __builtin_amdgcn_global_load_lds(
        (const __attribute__((address_space(1))) unsigned int*)g,
        (__attribute__((address_space(3))) unsigned int*)l, 16, 0, 0);
}

// ---------------- kernel 1: w_ah = hidden @ W_w + W_b  [128 x 512] ----------------
__global__ void wah_kernel(const float* __restrict__ hidden, const float* __restrict__ Ww,
                           const float* __restrict__ Wb, float* __restrict__ wah) {
    __shared__ __align__(16) float hs[DEC];
    const int b = blockIdx.x, a = threadIdx.x;   // block 512 threads
    hs[a] = hidden[b * DEC + a];
    __syncthreads();
    float acc = Wb[a];
    #pragma unroll 4
    for (int d = 0; d < DEC; d += 4) {
        f32x4 h = *(const f32x4*)&hs[d];
        acc += h.x * Ww[(d    ) * ADIM + a];
        acc += h.y * Ww[(d + 1) * ADIM + a];
        acc += h.z * Ww[(d + 2) * ADIM + a];
        acc += h.w * Ww[(d + 3) * ADIM + a];
    }
    wah[b * ADIM + a] = acc;
}

// ---------------- kernel 2: U_w [K=2048][N=512] fp32 -> uwT [N][K] bf16 ----------------
__global__ void transpose_uw(const float* __restrict__ Uw, unsigned short* __restrict__ uwT) {
    __shared__ float t[32][33];
    const int k0 = blockIdx.x * 32, n0 = blockIdx.y * 32;
    const int tx = threadIdx.x, ty = threadIdx.y;   // 32 x 8
    #pragma unroll
    for (int i = 0; i < 4; ++i)
        t[ty + 8 * i][tx] = Uw[(size_t)(k0 + ty + 8 * i) * ADIM + n0 + tx];
    __syncthreads();
    #pragma unroll
    for (int i = 0; i < 4; ++i)
        uwT[(size_t)(n0 + ty + 8 * i) * ENC + k0 + tx] = f2bf(t[tx][ty + 8 * i]);
}

// ---------------- kernel 3: fused GEMM + tanh + A_w-dot -> score partials ----------------
// OCCUPANCY-FIRST structure: BM=64 x BN=128 tiles -> grid 1568 (6.1 blocks/CU),
// 24KB single-buffer LDS, launch_bounds(256,4) -> ~4 resident blocks/CU; rely
// on implicit wave-level overlap (m114) instead of manual pipelining.
// Wave w covers all 64 rows x cols [w*32, w*32+32). acc 4x2 f32x4 = 32 VGPR.
// A: reg-staged fp32 -> cvt bf16 -> ds_write (tile [64][64] bf16, 128B rows,
//    16B-slot ^= row&7; write pattern 2-way per bank-slot = free).
// B: global_load_lds DMA, pre-swizzled source, linear dest (R5 pattern, 0 conflicts).
__global__ __launch_bounds__(256, 4) void gemm_score_kernel(
    const float* __restrict__ feat, const unsigned short* __restrict__ uwT,
    const float* __restrict__ Ub, const float* __restrict__ wahb,
    const float* __restrict__ Aw, float* __restrict__ part)
{
    __shared__ __align__(16) unsigned char As[8192];    // [64][64] bf16 swizzled
    __shared__ __align__(16) unsigned char Bs[16384];   // [128][64] bf16 swizzled

    const int tid  = threadIdx.x;
    const int lane = tid & 63;
    const int w    = tid >> 6;
    const int l15  = lane & 15, ldr = lane >> 4;

    // bijective XCD swizzle: 1568 blocks = 8 XCD chunks of 196 (nbk fastest)
    const int bid  = blockIdx.x;
    const int work = (bid & 7) * 196 + (bid >> 3);
    const int mb   = work >> 2;    // 0..391  (64-row tile)
    const int nbk  = work & 3;     // 0..3    (128-col tile)

    // ---- A global source: thread -> row tid>>2, 16-float chunk kq = tid&3 ----
    const int r_ = tid >> 2, kq = tid & 3;
    const float* aSrc = feat + (size_t)(mb * 64 + r_) * ENC + kq * 16;
    // ---- A ds_write offsets (16B slot ^= row&7): 2 x b128 per thread ----
    const int wA0 = r_ * 128 + (((kq * 2    ) ^ (r_ & 7)) << 4);
    const int wA1 = r_ * 128 + (((kq * 2 + 1) ^ (r_ & 7)) << 4);

    // ---- B DMA: wave w fills rows w*32..w*32+31; 4 chunks of 8 rows (1KB) ----
    // lane -> row lane>>3 (in chunk), slot lane&7; source pre-swizzled slot^(row&7)
    const unsigned short* bSrc = uwT
        + (size_t)(nbk * 128 + w * 32 + (lane >> 3)) * ENC
        + (((lane & 7) ^ ((lane >> 3) & 7)) << 3);

    // ---- fragment read byte offsets: slot (ks*4+ldr) ^ (row&7), row&7 == l15&7 ----
    int abyte[4][2], bbyte[2][2];
    #pragma unroll
    for (int ks = 0; ks < 2; ++ks) {
        const int sl = ((ks * 4 + ldr) ^ (l15 & 7)) << 4;
        #pragma unroll
        for (int f = 0; f < 4; ++f)
            abyte[f][ks] = (f * 16 + l15) * 128 + sl;
        #pragma unroll
        for (int g = 0; g < 2; ++g)
            bbyte[g][ks] = (w * 32 + g * 16 + l15) * 128 + sl;
    }

    f32x4 acc[4][2];
    #pragma unroll
    for (int i = 0; i < 4; ++i)
        #pragma unroll
        for (int j = 0; j < 2; ++j)
            acc[i][j] = (f32x4){0.f, 0.f, 0.f, 0.f};

    #pragma unroll 1
    for (int kt = 0; kt < NKT; ++kt) {
        // stage: A reg loads + B DMA (prev compute finished at loop-end barrier)
        const f32x4* p = (const f32x4*)(aSrc + (size_t)kt * 64);
        f32x4 a0 = p[0], a1 = p[1], a2 = p[2], a3 = p[3];
        #pragma unroll
        for (int c = 0; c < 4; ++c)
            load_lds16(bSrc + (size_t)kt * 64 + c * 8 * ENC, Bs + w * 4096 + c * 1024);
        // cvt + ds_write A (compiler inserts counted vmcnt for the 4 A loads)
        u32x4 w0, w1;
        w0.x = f2bf2(a0.x, a0.y); w0.y = f2bf2(a0.z, a0.w);
        w0.z = f2bf2(a1.x, a1.y); w0.w = f2bf2(a1.z, a1.w);
        w1.x = f2bf2(a2.x, a2.y); w1.y = f2bf2(a2.z, a2.w);
        w1.z = f2bf2(a3.x, a3.y); w1.w = f2bf2(a3.z, a3.w);
        *(u32x4*)(As + wA0) = w0;
        *(u32x4*)(As + wA1) = w1;
        __syncthreads();          // drains DMA (vmcnt) + ds_writes (lgkm): tile ready

        #pragma unroll
        for (int ks = 0; ks < 2; ++ks) {
            short8 af[4], bf[2];
            #pragma unroll
            for (int f = 0; f < 4; ++f) af[f] = *(const short8*)(As + abyte[f][ks]);
            #pragma unroll
            for (int g = 0; g < 2; ++g) bf[g] = *(const short8*)(Bs + bbyte[g][ks]);
            #pragma unroll
            for (int fm = 0; fm < 4; ++fm)
                #pragma unroll
                for (int g = 0; g < 2; ++g)
                    acc[fm][g] = __builtin_amdgcn_mfma_f32_16x16x32_bf16(
                        af[fm], bf[g], acc[fm][g], 0, 0, 0);
        }
        __syncthreads();          // reads done: next iter may overwrite tiles
    }

    // epilogue: score partial = sum_cols Aw[c]*tanh(acc + Ub[c] + wah[b][c])
    float ub2[2], aw2[2]; int cidx[2];
    #pragma unroll
    for (int g = 0; g < 2; ++g) {
        const int c = nbk * 128 + w * 32 + g * 16 + l15;
        cidx[g] = c; ub2[g] = Ub[c]; aw2[g] = Aw[c];
    }
    #pragma unroll
    for (int fm = 0; fm < 4; ++fm) {
        #pragma unroll
        for (int r = 0; r < 4; ++r) {
            const int m = mb * 64 + fm * 16 + ldr * 4 + r;
            const int b = m / NL;
            const float* wrow = wahb + b * ADIM;
            #pragma unroll
            for (int g = 0; g < 2; ++g) {
                float s = aw2[g] * tanhf(acc[fm][g][r] + ub2[g] + wrow[cidx[g]]);
                s += __shfl_xor(s, 1);
                s += __shfl_xor(s, 2);
                s += __shfl_xor(s, 4);
                s += __shfl_xor(s, 8);
                if (l15 == 0) part[(nbk * 8 + w * 2 + g) * MTOT + m] = s;
            }
        }
    }
}

// ---------------- kernel 4: reduce partials + softmax over L -> alpha ----------------
__global__ void softmax_kernel(const float* __restrict__ part, const float* __restrict__ Ab,
                               float* __restrict__ alpha) {
    const int b = blockIdx.x, t = threadIdx.x;   // 256 threads
    float sv = 0.f;
    if (t < NL) {
        sv = Ab[0];
        #pragma unroll 8
        for (int p = 0; p < NPART; ++p) sv += part[p * MTOT + b * NL + t];
    }
    float v = (t < NL) ? sv : -3.4e38f;
    #pragma unroll
    for (int o = 32; o >= 1; o >>= 1) v = fmaxf(v, __shfl_xor(v, o));
    __shared__ float rm[4], rs[4];
    if ((t & 63) == 0) rm[t >> 6] = v;
    __syncthreads();
    const float bm = fmaxf(fmaxf(rm[0], rm[1]), fmaxf(rm[2], rm[3]));
    const float e = (t < NL) ? expf(sv - bm) : 0.f;
    float s = e;
    #pragma unroll
    for (int o = 32; o >= 1; o >>= 1) s += __shfl_xor(s, o);
    if ((t & 63) == 0) rs[t >> 6] = s;
    __syncthreads();
    const float bs = rs[0] + rs[1] + rs[2] + rs[3];
    if (t < NL) alpha[b * NL + t] = e / bs;
}

// ---------------- kernel 5: context[b][e] = sum_l alpha[b][l] * feat[b][l][e] ----------------
__global__ void context_kernel(const float* __restrict__ feat, const float* __restrict__ alpha,
                               float* __restrict__ ctx) {
    __shared__ float al[NL];
    const int b = blockIdx.x, chunk = blockIdx.y, t = threadIdx.x;  // 128 threads
    for (int i = t; i < NL; i += 128) al[i] = alpha[b * NL + i];
    __syncthreads();
    const int e0 = chunk * 512 + t * 4;
    const float* fp = feat + (size_t)b * NL * ENC + e0;
    f32x4 acc0 = (f32x4){0.f, 0.f, 0.f, 0.f};
    f32x4 acc1 = (f32x4){0.f, 0.f, 0.f, 0.f};
    #pragma unroll 2
    for (int l = 0; l < NL; l += 2) {
        f32x4 f0 = *(const f32x4*)(fp + (size_t)l * ENC);
        f32x4 f1 = *(const f32x4*)(fp + (size_t)(l + 1) * ENC);
        acc0 += al[l] * f0;
        acc1 += al[l + 1] * f1;
    }
    f32x4 rsum = acc0 + acc1;
    *(f32x4*)(ctx + (size_t)b * ENC + e0) = rsum;
}

extern "C" void kernel_launch(void* const* d_in, const int* in_sizes, int n_in,
                              void* d_out, int out_size, void* d_ws, size_t ws_size,
                              hipStream_t stream) {
    const float* feat   = (const float*)d_in[0];
    const float* hidden = (const float*)d_in[1];
    const float* Uw     = (const float*)d_in[2];
    const float* Ub     = (const float*)d_in[3];
    const float* Ww     = (const float*)d_in[4];
    const float* Wb     = (const float*)d_in[5];
    const float* Aw     = (const float*)d_in[6];
    const float* Ab     = (const float*)d_in[7];

    float* out   = (float*)d_out;
    float* alpha = out;              // [128*196]
    float* ctx   = out + MTOT;       // [128*2048]

    char* ws = (char*)d_ws;
    float*          wahb = (float*)ws;                                   // 256 KB
    unsigned short* uwT  = (unsigned short*)(ws + 262144);               // 2 MB
    float*          partb= (float*)(ws + 262144 + 2097152);              // 32*25088*4 = 3.2 MB

    wah_kernel<<<dim3(128), dim3(512), 0, stream>>>(hidden, Ww, Wb, wahb);
    transpose_uw<<<dim3(64, 16), dim3(32, 8), 0, stream>>>(Uw, uwT);
    gemm_score_kernel<<<dim3(1568), dim3(256), 0, stream>>>(feat, uwT, Ub, wahb, Aw, partb);
    softmax_kernel<<<dim3(128), dim3(256), 0, stream>>>(partb, Ab, alpha);
    context_kernel<<<dim3(128, 4), dim3(128), 0, stream>>>(feat, alpha, ctx);
}